// Round 9
// baseline (116.214 us; speedup 1.0000x reference)
//
#include <hip/hip_runtime.h>
#include <hip/hip_bf16.h>
#include <math.h>

#define S_LEN 2048
#define DM    1024
#define NH    16
#define DH    64
#define CHUNK 64
#define NCH   (S_LEN / CHUNK)          // 32
#define ST_STRIDE (DH * DH + DH)       // 4160 floats per (head,chunk) state

typedef __attribute__((ext_vector_type(8))) short bf16x8;   // 8 bf16 in 4 VGPRs
typedef __attribute__((ext_vector_type(4))) float f32x4;

__device__ __forceinline__ float softplus_f(float x) {
    return (x > 20.0f) ? x : log1pf(expf(x));
}

__device__ __forceinline__ ushort bf16r(float f) {   // round-to-nearest-even f32 -> bf16
    union { float f; unsigned int u; } c; c.f = f;
    unsigned int u = c.u;
    u = (u + 0x7FFFu + ((u >> 16) & 1u)) >> 16;
    return (ushort)u;
}

// ---------------- casts ----------------
__global__ __launch_bounds__(256) void cast_x_kernel(const float* __restrict__ src,
                                                     ushort* __restrict__ dst) {
    const int i = (blockIdx.x * 256 + threadIdx.x) * 4;
    const float4 v = *(const float4*)(src + i);
    ushort4 o; o.x = bf16r(v.x); o.y = bf16r(v.y); o.z = bf16r(v.z); o.w = bf16r(v.w);
    *(ushort4*)(dst + i) = o;
}

__global__ __launch_bounds__(256) void cast_w_kernel(const float* __restrict__ Wq,
                                                     const float* __restrict__ Wk,
                                                     const float* __restrict__ Wv,
                                                     const float* __restrict__ Wo,
                                                     ushort* __restrict__ dst) {
    const int y = blockIdx.y;
    const float* s = (y == 0) ? Wq : (y == 1) ? Wk : (y == 2) ? Wv : Wo;
    const int i = (blockIdx.x * 256 + threadIdx.x) * 4;
    const float4 v = *(const float4*)(s + i);
    ushort4 o; o.x = bf16r(v.x); o.y = bf16r(v.y); o.z = bf16r(v.z); o.w = bf16r(v.w);
    *(ushort4*)(dst + (size_t)y * (DM * DM) + i) = o;
}

// ============ QKV GEMM: BM=64 x BN=128, BK=64 -> 16 K-steps (barrier-count A/B) ============
// A=Xb [2048][1024], B=Wqkv [3072][1024] (Wq|Wk|Wv).  768 blocks (3/CU), 4 waves (2x2),
// wave tile 32x64 (MF=2 x NF=4, 2 k-subs).  LDS 24KB single-buffered.
// Same staged bytes / occupancy as R8; HALF the barrier-lockstep steps.  If R4-R8's ~48us
// invariance is per-step lockstep cost, this lands ~32us; if per-byte, ~48 again.
// Swizzle for 64-elem rows: row r's eight 16B granules permuted g_phys = g ^ (r&7)
// (involution; linear gload_lds dest + inverse-swizzled global source col, rule 21;
// fragment reads apply the same XOR -> 8 distinct bank-quads, 2 lanes each = free).
__global__ __launch_bounds__(256)
void qkv_gemm_kernel(const ushort* __restrict__ Xb, const ushort* __restrict__ Wqkv,
                     const float* __restrict__ bq, const float* __restrict__ bk,
                     const float* __restrict__ bv,
                     const float* __restrict__ beta,
                     float* __restrict__ qkv /* q|k|v contiguous */)
{
    __shared__ ushort Als[64 * 64];    // 8 KB
    __shared__ ushort Bls[128 * 64];   // 16 KB

    const int b = blockIdx.x;
    const int logical = (b & 7) * 96 + (b >> 3);      // XCD-bijective (768%8==0)
    const int mb = logical & 31, nb = logical >> 5;   // m-fastest within XCD
    const int m0 = mb * 64, n0 = nb * 128;
    const int z  = nb >> 3;                           // 0:q 1:k 2:v
    const int nz0 = (nb & 7) * 128;
    const float* bias = (z == 0) ? bq : (z == 1) ? bk : bv;

    const int t = threadIdx.x, w = t >> 6, l = t & 63;
    const int wr = w >> 1, wc = w & 1;                // 2x2 wave grid
    const int r8 = l >> 3;                            // staging row within 8-row instr
    const int scol = ((l & 7) ^ r8) * 8;              // inverse-swizzled source col (elems)
    const int frow = l & 15, kq = l >> 4;

    f32x4 acc[2][4];
#pragma unroll
    for (int mi = 0; mi < 2; ++mi)
#pragma unroll
        for (int ni = 0; ni < 4; ++ni) acc[mi][ni] = (f32x4){0.f, 0.f, 0.f, 0.f};

    for (int kt = 0; kt < DM; kt += 64) {
        // stage: 24 gload instrs (A: 8, B: 16), wave w handles instr w+4*k2
#pragma unroll
        for (int k2 = 0; k2 < 6; ++k2) {
            const int idx = w + 4 * k2;
            if (idx < 8) {             // A rows 8*idx .. 8*idx+7
                __builtin_amdgcn_global_load_lds(
                    (const __attribute__((address_space(1))) void*)(Xb + (size_t)(m0 + idx * 8 + r8) * DM + kt + scol),
                    (__attribute__((address_space(3))) void*)(Als + idx * 512), 16, 0, 0);
            } else {                   // B rows 8*(idx-8) ..
                const int ib = idx - 8;
                __builtin_amdgcn_global_load_lds(
                    (const __attribute__((address_space(1))) void*)(Wqkv + (size_t)(n0 + ib * 8 + r8) * DM + kt + scol),
                    (__attribute__((address_space(3))) void*)(Bls + ib * 512), 16, 0, 0);
            }
        }
        __syncthreads();   // staged data visible

#pragma unroll
        for (int ks = 0; ks < 2; ++ks) {
            bf16x8 af[2], bf[4];
#pragma unroll
            for (int mi = 0; mi < 2; ++mi) {
                const int rr = wr * 32 + mi * 16 + frow;
                af[mi] = *(const bf16x8*)&Als[rr * 64 + (((kq + 4 * ks) ^ (rr & 7)) << 3)];
            }
#pragma unroll
            for (int ni = 0; ni < 4; ++ni) {
                const int rr = wc * 64 + ni * 16 + frow;
                bf[ni] = *(const bf16x8*)&Bls[rr * 64 + (((kq + 4 * ks) ^ (rr & 7)) << 3)];
            }
#pragma unroll
            for (int mi = 0; mi < 2; ++mi)
#pragma unroll
                for (int ni = 0; ni < 4; ++ni)
                    acc[mi][ni] = __builtin_amdgcn_mfma_f32_16x16x32_bf16(af[mi], bf[ni], acc[mi][ni], 0, 0, 0);
        }
        __syncthreads();   // protect LDS before next stage
    }

    float* outz = qkv + (size_t)z * (NH * S_LEN * DH);
#pragma unroll
    for (int ni = 0; ni < 4; ++ni) {
        const int col = nz0 + wc * 64 + ni * 16 + (l & 15);
        const int h = col >> 6, d = col & 63;
        const float bcol = bias[col];
        const float inv = (z < 2) ? (1.0f / (8.0f * expf(beta[h]))) : 1.0f;
#pragma unroll
        for (int mi = 0; mi < 2; ++mi) {
            const int rbase = m0 + wr * 32 + mi * 16 + (l >> 4) * 4;
#pragma unroll
            for (int r = 0; r < 4; ++r) {
                float v = acc[mi][ni][r] + bcol;
                if (z < 2) v = softplus_f(v * inv);
                outz[((size_t)h * S_LEN + rbase + r) * DH + d] = v;
            }
        }
    }
}

// ============ O projection: REG-DIRECT, zero-LDS, zero-barrier (sync-elimination A/B) ======
// C = op_bf @ Wo^T + bo.  512 blocks (2/CU), 4 waves (2x2), wave tile 32x32 (MF=NF=2).
// MFMA operand fragments load STRAIGHT from global (L2-hot; X panel 4MB, Wo 2MB): no LDS,
// no __syncthreads, no vmcnt drains.  Unroll-4 gives 16 loads in flight per wave; 8 waves/CU
// TLP on top.  2x L2 traffic vs LDS-staged (intra-block redundancy) -- the A/B: if o_gemm's
// cost was sync/latency it drops to ~5-7us; if L2 bytes, it regresses.
__global__ __launch_bounds__(256)
void o_gemm_kernel(const ushort* __restrict__ Ab, const ushort* __restrict__ Wob,
                   const float* __restrict__ bo, float* __restrict__ out)
{
    const int b = blockIdx.x;
    const int logical = (b & 7) * 64 + (b >> 3);
    const int mb = logical & 31, nb = logical >> 5;   // 32 x 16 tiles of 64x64
    const int m0 = mb * 64, n0 = nb * 64;

    const int t = threadIdx.x, w = t >> 6, l = t & 63;
    const int wr = w >> 1, wc = w & 1;
    const int frow = l & 15, kq = l >> 4;

    // per-lane row bases (constant over K)
    const ushort* arow0 = Ab  + (size_t)(m0 + wr * 32 +  0 + frow) * DM + kq * 8;
    const ushort* arow1 = Ab  + (size_t)(m0 + wr * 32 + 16 + frow) * DM + kq * 8;
    const ushort* brow0 = Wob + (size_t)(n0 + wc * 32 +  0 + frow) * DM + kq * 8;
    const ushort* brow1 = Wob + (size_t)(n0 + wc * 32 + 16 + frow) * DM + kq * 8;

    f32x4 acc[2][2];
#pragma unroll
    for (int mi = 0; mi < 2; ++mi)
#pragma unroll
        for (int ni = 0; ni < 2; ++ni) acc[mi][ni] = (f32x4){0.f, 0.f, 0.f, 0.f};

#pragma unroll 4
    for (int kt = 0; kt < DM; kt += 32) {
        const bf16x8 a0 = *(const bf16x8*)(arow0 + kt);
        const bf16x8 a1 = *(const bf16x8*)(arow1 + kt);
        const bf16x8 b0 = *(const bf16x8*)(brow0 + kt);
        const bf16x8 b1 = *(const bf16x8*)(brow1 + kt);
        acc[0][0] = __builtin_amdgcn_mfma_f32_16x16x32_bf16(a0, b0, acc[0][0], 0, 0, 0);
        acc[0][1] = __builtin_amdgcn_mfma_f32_16x16x32_bf16(a0, b1, acc[0][1], 0, 0, 0);
        acc[1][0] = __builtin_amdgcn_mfma_f32_16x16x32_bf16(a1, b0, acc[1][0], 0, 0, 0);
        acc[1][1] = __builtin_amdgcn_mfma_f32_16x16x32_bf16(a1, b1, acc[1][1], 0, 0, 0);
    }

#pragma unroll
    for (int ni = 0; ni < 2; ++ni) {
        const int col = n0 + wc * 32 + ni * 16 + (l & 15);
        const float bcol = bo[col];
#pragma unroll
        for (int mi = 0; mi < 2; ++mi) {
            const int rbase = m0 + wr * 32 + mi * 16 + (l >> 4) * 4;
#pragma unroll
            for (int r = 0; r < 4; ++r)
                out[(size_t)(rbase + r) * DM + col] = acc[mi][ni][r] + bcol;
        }
    }
}

// ---------------- Pass B: per (head, chunk) state ----------------
__global__ __launch_bounds__(256)
void chunk_state_kernel(const float* __restrict__ k_ws, const float* __restrict__ v_ws,
                        float* __restrict__ st)
{
    __shared__ float Ks[64][64];
    __shared__ float Vs[64][64];
    const int c = blockIdx.x, h = blockIdx.y;
    const int t = threadIdx.x;
    const float* Kg = k_ws + ((size_t)h * S_LEN + c * CHUNK) * DH;
    const float* Vg = v_ws + ((size_t)h * S_LEN + c * CHUNK) * DH;
#pragma unroll
    for (int u = 0; u < 4; ++u) {
        int f = u * 256 + t;
        ((float4*)&Ks[0][0])[f] = ((const float4*)Kg)[f];
        ((float4*)&Vs[0][0])[f] = ((const float4*)Vg)[f];
    }
    __syncthreads();

    const int tx = t & 15, ty = t >> 4;
    float acc[4][4];
#pragma unroll
    for (int i = 0; i < 4; ++i)
#pragma unroll
        for (int j = 0; j < 4; ++j) acc[i][j] = 0.0f;

    for (int s = 0; s < 64; ++s) {
        const float4 kd = *(const float4*)&Ks[s][ty * 4];
        const float4 ve = *(const float4*)&Vs[s][tx * 4];
        const float kv[4] = {kd.x, kd.y, kd.z, kd.w};
        const float vv[4] = {ve.x, ve.y, ve.z, ve.w};
#pragma unroll
        for (int i = 0; i < 4; ++i)
#pragma unroll
            for (int j = 0; j < 4; ++j) acc[i][j] += kv[i] * vv[j];
    }
    float* base = st + (size_t)(h * NCH + c) * ST_STRIDE;
#pragma unroll
    for (int i = 0; i < 4; ++i) {
        float4 o; o.x = acc[i][0]; o.y = acc[i][1]; o.z = acc[i][2]; o.w = acc[i][3];
        *(float4*)(base + (ty * 4 + i) * 64 + tx * 4) = o;
    }
    if (t < 64) {
        float s = 0.0f;
        for (int j = 0; j < 64; ++j) s += Ks[j][t];
        base[DH * DH + t] = s;
    }
}

// ---------------- Pass C: in-place exclusive prefix scan over chunks ----------------
__global__ __launch_bounds__(64)
void scan_kernel(float* __restrict__ st)
{
    const int h = blockIdx.y;
    const int e = blockIdx.x * 64 + threadIdx.x;
    float* p = st + (size_t)h * NCH * ST_STRIDE + e;
    float acc = 0.0f;
    for (int c = 0; c < NCH; ++c) {
        const float v = p[(size_t)c * ST_STRIDE];
        p[(size_t)c * ST_STRIDE] = acc;
        acc += v;
    }
}

// ---------------- Pass D: per (head, chunk) output ----------------
__global__ __launch_bounds__(256)
void attn_out_kernel(const float* __restrict__ q_ws, const float* __restrict__ k_ws,
                     const float* __restrict__ v_ws, const float* __restrict__ pfx,
                     ushort* __restrict__ out_pre)
{
    __shared__ float QsT[64][68];   // [d][i]
    __shared__ float KsT[64][68];   // [d][j]
    __shared__ float Vs[64][64];    // [j][e]
    __shared__ float As[64][65];    // [i][j]

    const int c = blockIdx.x, h = blockIdx.y;
    const int t = threadIdx.x, tx = t & 15, ty = t >> 4;
    const size_t cbase = ((size_t)h * S_LEN + c * CHUNK) * DH;
    const float* __restrict__ pb = pfx + (size_t)(h * NCH + c) * ST_STRIDE;

#pragma unroll
    for (int u = 0; u < 4; ++u) {
        int f = u * 256 + t;
        int cg = f >> 6, row = f & 63;
        const int col4 = cg * 4;
        const float4 qv = *(const float4*)(q_ws + cbase + (size_t)row * DH + col4);
        QsT[col4 + 0][row] = qv.x;
        QsT[col4 + 1][row] = qv.y;
        QsT[col4 + 2][row] = qv.z;
        QsT[col4 + 3][row] = qv.w;
        const float4 kv = *(const float4*)(k_ws + cbase + (size_t)row * DH + col4);
        KsT[col4 + 0][row] = kv.x;
        KsT[col4 + 1][row] = kv.y;
        KsT[col4 + 2][row] = kv.z;
        KsT[col4 + 3][row] = kv.w;
    }
#pragma unroll
    for (int u = 0; u < 4; ++u) {
        int f = u * 256 + t;
        ((float4*)&Vs[0][0])[f] = ((const float4*)(v_ws + cbase))[f];
    }
    __syncthreads();

    float a[4][4];
#pragma unroll
    for (int i = 0; i < 4; ++i)
#pragma unroll
        for (int j = 0; j < 4; ++j) a[i][j] = 0.0f;
    for (int d = 0; d < 64; ++d) {
        const float4 qd = *(const float4*)&QsT[d][ty * 4];
        const float4 kd = *(const float4*)&KsT[d][tx * 4];
        const float qv[4] = {qd.x, qd.y, qd.z, qd.w};
        const float kv[4] = {kd.x, kd.y, kd.z, kd.w};
#pragma unroll
        for (int i = 0; i < 4; ++i)
#pragma unroll
            for (int j = 0; j < 4; ++j) a[i][j] += qv[i] * kv[j];
    }
#pragma unroll
    for (int i = 0; i < 4; ++i)
#pragma unroll
        for (int j = 0; j < 4; ++j) {
            const int gi = ty * 4 + i, gj = tx * 4 + j;
            As[gi][gj] = (gj <= gi) ? a[i][j] : 0.0f;
        }

    float num[4][4];
#pragma unroll
    for (int i = 0; i < 4; ++i)
#pragma unroll
        for (int j = 0; j < 4; ++j) num[i][j] = 0.0f;
    float den[4] = {0.0f, 0.0f, 0.0f, 0.0f};
#pragma unroll 4
    for (int d = 0; d < 64; ++d) {
        const float4 qd = *(const float4*)&QsT[d][ty * 4];
        const float4 pe = *(const float4*)(pb + d * 64 + tx * 4);
        const float kp = pb[DH * DH + d];
        const float qv[4] = {qd.x, qd.y, qd.z, qd.w};
        const float pv[4] = {pe.x, pe.y, pe.z, pe.w};
#pragma unroll
        for (int i = 0; i < 4; ++i) {
#pragma unroll
            for (int j = 0; j < 4; ++j) num[i][j] += qv[i] * pv[j];
            den[i] += qv[i] * kp;
        }
    }
    __syncthreads();

    float rs[4] = {0.0f, 0.0f, 0.0f, 0.0f};
    for (int j = 0; j < 64; ++j) {
        const float4 ve = *(const float4*)&Vs[j][tx * 4];
        const float vv[4] = {ve.x, ve.y, ve.z, ve.w};
#pragma unroll
        for (int i = 0; i < 4; ++i) {
            const float aij = As[ty * 4 + i][j];
            rs[i] += aij;
            num[i][0] += aij * vv[0];
            num[i][1] += aij * vv[1];
            num[i][2] += aij * vv[2];
            num[i][3] += aij * vv[3];
        }
    }

#pragma unroll
    for (int i = 0; i < 4; ++i) {
        const float dn = den[i] + rs[i];
        const float r  = 1.0f / dn;
        const int srow = c * CHUNK + ty * 4 + i;
        ushort4 o;
        o.x = bf16r(num[i][0] * r); o.y = bf16r(num[i][1] * r);
        o.z = bf16r(num[i][2] * r); o.w = bf16r(num[i][3] * r);
        *(ushort4*)(out_pre + (size_t)srow * DM + h * DH + tx * 4) = o;
    }
}

extern "C" void kernel_launch(void* const* d_in, const int* in_sizes, int n_in,
                              void* d_out, int out_size, void* d_ws, size_t ws_size,
                              hipStream_t stream)
{
    const float* x    = (const float*)d_in[0];
    const float* Wq   = (const float*)d_in[1];
    const float* bq   = (const float*)d_in[2];
    const float* Wk   = (const float*)d_in[3];
    const float* bk   = (const float*)d_in[4];
    const float* Wv   = (const float*)d_in[5];
    const float* bv   = (const float*)d_in[6];
    const float* Wo   = (const float*)d_in[7];
    const float* bo   = (const float*)d_in[8];
    const float* beta = (const float*)d_in[9];
    float* out = (float*)d_out;

    float*  q_ws  = (float*)d_ws;                          // 3 x 2M floats (q|k|v)
    float*  k_ws  = q_ws + (size_t)NH * S_LEN * DH;
    float*  v_ws  = k_ws + (size_t)NH * S_LEN * DH;
    float*  st    = v_ws + (size_t)NH * S_LEN * DH;        // 16*32*4160 floats
    ushort* x_bf  = (ushort*)(st + (size_t)NH * NCH * ST_STRIDE);   // 2M bf16
    ushort* w_bf  = x_bf + (size_t)S_LEN * DM;                      // 4 x 1M bf16 (Wq|Wk|Wv|Wo)
    ushort* op_bf = w_bf + (size_t)4 * DM * DM;                     // 2M bf16

    const ushort* wo_bf = w_bf + (size_t)3 * DM * DM;

    cast_x_kernel<<<(S_LEN * DM) / 1024, 256, 0, stream>>>(x, x_bf);
    cast_w_kernel<<<dim3((DM * DM) / 1024, 4), 256, 0, stream>>>(Wq, Wk, Wv, Wo, w_bf);

    qkv_gemm_kernel<<<768, 256, 0, stream>>>(x_bf, w_bf, bq, bk, bv, beta, q_ws);

    chunk_state_kernel<<<dim3(NCH, NH), 256, 0, stream>>>(k_ws, v_ws, st);
    scan_kernel<<<dim3(ST_STRIDE / 64, NH), 64, 0, stream>>>(st);
    attn_out_kernel<<<dim3(NCH, NH), 256, 0, stream>>>(q_ws, k_ws, v_ws, st, op_bf);

    o_gemm_kernel<<<512, 256, 0, stream>>>(op_bf, wo_bf, bo, out);
}

// Round 10
// 94.629 us; speedup vs baseline: 1.2281x; 1.2281x over previous
//
#include <hip/hip_runtime.h>
#include <hip/hip_bf16.h>
#include <math.h>

#define S_LEN 2048
#define DM    1024
#define NH    16
#define DH    64
#define CHUNK 64
#define NCH   (S_LEN / CHUNK)          // 32
#define ST_STRIDE (DH * DH + DH)       // 4160 floats per (head,chunk) state

typedef __attribute__((ext_vector_type(8))) short bf16x8;   // 8 bf16 in 4 VGPRs
typedef __attribute__((ext_vector_type(4))) float f32x4;

__device__ __forceinline__ float softplus_f(float x) {
    return (x > 20.0f) ? x : log1pf(expf(x));
}

__device__ __forceinline__ ushort bf16r(float f) {   // round-to-nearest-even f32 -> bf16
    union { float f; unsigned int u; } c; c.f = f;
    unsigned int u = c.u;
    u = (u + 0x7FFFu + ((u >> 16) & 1u)) >> 16;
    return (ushort)u;
}

__device__ __forceinline__ float b2f(ushort u) {     // bf16 -> f32 (shift)
    union { unsigned int i; float f; } c; c.i = ((unsigned int)u) << 16;
    return c.f;
}

// ---------------- fused cast: x (2 slabs) + 4 weights, one launch ----------------
__global__ __launch_bounds__(256)
void cast_all_kernel(const float* __restrict__ x,
                     const float* __restrict__ Wq, const float* __restrict__ Wk,
                     const float* __restrict__ Wv, const float* __restrict__ Wo,
                     ushort* __restrict__ x_bf, ushort* __restrict__ w_bf)
{
    const int y = blockIdx.y;          // 0,1: x halves; 2..5: Wq,Wk,Wv,Wo
    const float* src;
    ushort* dst;
    if (y < 2) { src = x + (size_t)y * (DM * DM);  dst = x_bf + (size_t)y * (DM * DM); }
    else {
        const float* ws[4] = {Wq, Wk, Wv, Wo};
        src = ws[y - 2];  dst = w_bf + (size_t)(y - 2) * (DM * DM);
    }
    const int i = (blockIdx.x * 256 + threadIdx.x) * 4;
    const float4 v = *(const float4*)(src + i);
    ushort4 o; o.x = bf16r(v.x); o.y = bf16r(v.y); o.z = bf16r(v.z); o.w = bf16r(v.w);
    *(ushort4*)(dst + i) = o;
}

// ============ QKV GEMM: BM=64 x BN=128, BK=64, 768 blocks (3/CU) — R9-proven, bf16 out ======
// Swizzle (verified 0-conflict): 8-row 1KB chunks; row r's eight 16B granules permuted
// g_phys = g ^ (r&7); linear gload_lds dest + inverse-swizzled global source col (rule 21);
// fragment reads apply the same XOR.
__global__ __launch_bounds__(256)
void qkv_gemm_kernel(const ushort* __restrict__ Xb, const ushort* __restrict__ Wqkv,
                     const float* __restrict__ bq, const float* __restrict__ bk,
                     const float* __restrict__ bv,
                     const float* __restrict__ beta,
                     ushort* __restrict__ qkv /* q|k|v contiguous, bf16 head layout */)
{
    __shared__ ushort Als[64 * 64];    // 8 KB
    __shared__ ushort Bls[128 * 64];   // 16 KB

    const int b = blockIdx.x;
    const int logical = (b & 7) * 96 + (b >> 3);      // XCD-bijective (768%8==0)
    const int mb = logical & 31, nb = logical >> 5;   // m-fastest within XCD
    const int m0 = mb * 64, n0 = nb * 128;
    const int z  = nb >> 3;                           // 0:q 1:k 2:v
    const int nz0 = (nb & 7) * 128;
    const float* bias = (z == 0) ? bq : (z == 1) ? bk : bv;

    const int t = threadIdx.x, w = t >> 6, l = t & 63;
    const int wr = w >> 1, wc = w & 1;                // 2x2 wave grid
    const int r8 = l >> 3;
    const int scol = ((l & 7) ^ r8) * 8;              // inverse-swizzled source col (elems)
    const int frow = l & 15, kq = l >> 4;

    f32x4 acc[2][4];
#pragma unroll
    for (int mi = 0; mi < 2; ++mi)
#pragma unroll
        for (int ni = 0; ni < 4; ++ni) acc[mi][ni] = (f32x4){0.f, 0.f, 0.f, 0.f};

    for (int kt = 0; kt < DM; kt += 64) {
#pragma unroll
        for (int k2 = 0; k2 < 6; ++k2) {
            const int idx = w + 4 * k2;
            if (idx < 8) {
                __builtin_amdgcn_global_load_lds(
                    (const __attribute__((address_space(1))) void*)(Xb + (size_t)(m0 + idx * 8 + r8) * DM + kt + scol),
                    (__attribute__((address_space(3))) void*)(Als + idx * 512), 16, 0, 0);
            } else {
                const int ib = idx - 8;
                __builtin_amdgcn_global_load_lds(
                    (const __attribute__((address_space(1))) void*)(Wqkv + (size_t)(n0 + ib * 8 + r8) * DM + kt + scol),
                    (__attribute__((address_space(3))) void*)(Bls + ib * 512), 16, 0, 0);
            }
        }
        __syncthreads();

#pragma unroll
        for (int ks = 0; ks < 2; ++ks) {
            bf16x8 af[2], bf[4];
#pragma unroll
            for (int mi = 0; mi < 2; ++mi) {
                const int rr = wr * 32 + mi * 16 + frow;
                af[mi] = *(const bf16x8*)&Als[rr * 64 + (((kq + 4 * ks) ^ (rr & 7)) << 3)];
            }
#pragma unroll
            for (int ni = 0; ni < 4; ++ni) {
                const int rr = wc * 64 + ni * 16 + frow;
                bf[ni] = *(const bf16x8*)&Bls[rr * 64 + (((kq + 4 * ks) ^ (rr & 7)) << 3)];
            }
#pragma unroll
            for (int mi = 0; mi < 2; ++mi)
#pragma unroll
                for (int ni = 0; ni < 4; ++ni)
                    acc[mi][ni] = __builtin_amdgcn_mfma_f32_16x16x32_bf16(af[mi], bf[ni], acc[mi][ni], 0, 0, 0);
        }
        __syncthreads();
    }

    ushort* outz = qkv + (size_t)z * (NH * S_LEN * DH);
#pragma unroll
    for (int ni = 0; ni < 4; ++ni) {
        const int col = nz0 + wc * 64 + ni * 16 + (l & 15);
        const int h = col >> 6, d = col & 63;
        const float bcol = bias[col];
        const float inv = (z < 2) ? (1.0f / (8.0f * expf(beta[h]))) : 1.0f;
#pragma unroll
        for (int mi = 0; mi < 2; ++mi) {
            const int rbase = m0 + wr * 32 + mi * 16 + (l >> 4) * 4;
#pragma unroll
            for (int r = 0; r < 4; ++r) {
                float v = acc[mi][ni][r] + bcol;
                if (z < 2) v = softplus_f(v * inv);
                outz[((size_t)h * S_LEN + rbase + r) * DH + d] = bf16r(v);
            }
        }
    }
}

// ============ O projection: LDS-staged (reg-direct A/B loser reverted), BK=64 ============
// C = op_bf @ Wo^T + bo -> fp32.  BM=64 x BN=64, 512 blocks (2/CU), 4 waves (2x2), 16 K-steps.
__global__ __launch_bounds__(256)
void o_gemm_kernel(const ushort* __restrict__ Ab, const ushort* __restrict__ Wob,
                   const float* __restrict__ bo, float* __restrict__ out)
{
    __shared__ ushort Als[64 * 64];    // 8 KB
    __shared__ ushort Bls[64 * 64];    // 8 KB

    const int b = blockIdx.x;
    const int logical = (b & 7) * 64 + (b >> 3);      // XCD-bijective (512%8==0)
    const int mb = logical & 31, nb = logical >> 5;   // 32 x 16 tiles
    const int m0 = mb * 64, n0 = nb * 64;

    const int t = threadIdx.x, w = t >> 6, l = t & 63;
    const int wr = w >> 1, wc = w & 1;
    const int r8 = l >> 3;
    const int scol = ((l & 7) ^ r8) * 8;
    const int frow = l & 15, kq = l >> 4;

    f32x4 acc[2][2];
#pragma unroll
    for (int mi = 0; mi < 2; ++mi)
#pragma unroll
        for (int ni = 0; ni < 2; ++ni) acc[mi][ni] = (f32x4){0.f, 0.f, 0.f, 0.f};

    for (int kt = 0; kt < DM; kt += 64) {
#pragma unroll
        for (int k2 = 0; k2 < 4; ++k2) {
            const int idx = w + 4 * k2;                // 0..15
            if (idx < 8) {
                __builtin_amdgcn_global_load_lds(
                    (const __attribute__((address_space(1))) void*)(Ab + (size_t)(m0 + idx * 8 + r8) * DM + kt + scol),
                    (__attribute__((address_space(3))) void*)(Als + idx * 512), 16, 0, 0);
            } else {
                const int ib = idx - 8;
                __builtin_amdgcn_global_load_lds(
                    (const __attribute__((address_space(1))) void*)(Wob + (size_t)(n0 + ib * 8 + r8) * DM + kt + scol),
                    (__attribute__((address_space(3))) void*)(Bls + ib * 512), 16, 0, 0);
            }
        }
        __syncthreads();

#pragma unroll
        for (int ks = 0; ks < 2; ++ks) {
            bf16x8 af[2], bf[2];
#pragma unroll
            for (int mi = 0; mi < 2; ++mi) {
                const int rr = wr * 32 + mi * 16 + frow;
                af[mi] = *(const bf16x8*)&Als[rr * 64 + (((kq + 4 * ks) ^ (rr & 7)) << 3)];
            }
#pragma unroll
            for (int ni = 0; ni < 2; ++ni) {
                const int rr = wc * 32 + ni * 16 + frow;
                bf[ni] = *(const bf16x8*)&Bls[rr * 64 + (((kq + 4 * ks) ^ (rr & 7)) << 3)];
            }
#pragma unroll
            for (int mi = 0; mi < 2; ++mi)
#pragma unroll
                for (int ni = 0; ni < 2; ++ni)
                    acc[mi][ni] = __builtin_amdgcn_mfma_f32_16x16x32_bf16(af[mi], bf[ni], acc[mi][ni], 0, 0, 0);
        }
        __syncthreads();
    }

#pragma unroll
    for (int ni = 0; ni < 2; ++ni) {
        const int col = n0 + wc * 32 + ni * 16 + (l & 15);
        const float bcol = bo[col];
#pragma unroll
        for (int mi = 0; mi < 2; ++mi) {
            const int rbase = m0 + wr * 32 + mi * 16 + (l >> 4) * 4;
#pragma unroll
            for (int r = 0; r < 4; ++r)
                out[(size_t)(rbase + r) * DM + col] = acc[mi][ni][r] + bcol;
        }
    }
}

// ---------------- Pass B: per (head, chunk) state (bf16 k/v inputs) ----------------
__global__ __launch_bounds__(256)
void chunk_state_kernel(const ushort* __restrict__ k_ws, const ushort* __restrict__ v_ws,
                        float* __restrict__ st)
{
    __shared__ float Ks[64][64];
    __shared__ float Vs[64][64];
    const int c = blockIdx.x, h = blockIdx.y;
    const int t = threadIdx.x;
    const ushort* Kg = k_ws + ((size_t)h * S_LEN + c * CHUNK) * DH;
    const ushort* Vg = v_ws + ((size_t)h * S_LEN + c * CHUNK) * DH;
#pragma unroll
    for (int u = 0; u < 4; ++u) {
        int f = u * 256 + t;                           // 1024 ushort4 each (4096 elems)
        const ushort4 k4 = ((const ushort4*)Kg)[f];
        const ushort4 v4 = ((const ushort4*)Vg)[f];
        float* kp = &Ks[0][0] + f * 4;
        float* vp = &Vs[0][0] + f * 4;
        kp[0] = b2f(k4.x); kp[1] = b2f(k4.y); kp[2] = b2f(k4.z); kp[3] = b2f(k4.w);
        vp[0] = b2f(v4.x); vp[1] = b2f(v4.y); vp[2] = b2f(v4.z); vp[3] = b2f(v4.w);
    }
    __syncthreads();

    const int tx = t & 15, ty = t >> 4;
    float acc[4][4];
#pragma unroll
    for (int i = 0; i < 4; ++i)
#pragma unroll
        for (int j = 0; j < 4; ++j) acc[i][j] = 0.0f;

    for (int s = 0; s < 64; ++s) {
        const float4 kd = *(const float4*)&Ks[s][ty * 4];
        const float4 ve = *(const float4*)&Vs[s][tx * 4];
        const float kv[4] = {kd.x, kd.y, kd.z, kd.w};
        const float vv[4] = {ve.x, ve.y, ve.z, ve.w};
#pragma unroll
        for (int i = 0; i < 4; ++i)
#pragma unroll
            for (int j = 0; j < 4; ++j) acc[i][j] += kv[i] * vv[j];
    }
    float* base = st + (size_t)(h * NCH + c) * ST_STRIDE;
#pragma unroll
    for (int i = 0; i < 4; ++i) {
        float4 o; o.x = acc[i][0]; o.y = acc[i][1]; o.z = acc[i][2]; o.w = acc[i][3];
        *(float4*)(base + (ty * 4 + i) * 64 + tx * 4) = o;
    }
    if (t < 64) {
        float s = 0.0f;
        for (int j = 0; j < 64; ++j) s += Ks[j][t];
        base[DH * DH + t] = s;
    }
}

// ---------------- Pass C: in-place exclusive prefix scan over chunks ----------------
__global__ __launch_bounds__(64)
void scan_kernel(float* __restrict__ st)
{
    const int h = blockIdx.y;
    const int e = blockIdx.x * 64 + threadIdx.x;
    float* p = st + (size_t)h * NCH * ST_STRIDE + e;
    float acc = 0.0f;
    for (int c = 0; c < NCH; ++c) {
        const float v = p[(size_t)c * ST_STRIDE];
        p[(size_t)c * ST_STRIDE] = acc;
        acc += v;
    }
}

// ---------------- Pass D: per (head, chunk) output (bf16 q/k/v inputs) ----------------
__global__ __launch_bounds__(256)
void attn_out_kernel(const ushort* __restrict__ q_ws, const ushort* __restrict__ k_ws,
                     const ushort* __restrict__ v_ws, const float* __restrict__ pfx,
                     ushort* __restrict__ out_pre)
{
    __shared__ float QsT[64][68];   // [d][i]
    __shared__ float KsT[64][68];   // [d][j]
    __shared__ float Vs[64][64];    // [j][e]
    __shared__ float As[64][65];    // [i][j]

    const int c = blockIdx.x, h = blockIdx.y;
    const int t = threadIdx.x, tx = t & 15, ty = t >> 4;
    const size_t cbase = ((size_t)h * S_LEN + c * CHUNK) * DH;
    const float* __restrict__ pb = pfx + (size_t)(h * NCH + c) * ST_STRIDE;

#pragma unroll
    for (int u = 0; u < 4; ++u) {
        int f = u * 256 + t;
        int cg = f >> 6, row = f & 63;
        const int col4 = cg * 4;
        const ushort4 q4 = *(const ushort4*)(q_ws + cbase + (size_t)row * DH + col4);
        QsT[col4 + 0][row] = b2f(q4.x);
        QsT[col4 + 1][row] = b2f(q4.y);
        QsT[col4 + 2][row] = b2f(q4.z);
        QsT[col4 + 3][row] = b2f(q4.w);
        const ushort4 k4 = *(const ushort4*)(k_ws + cbase + (size_t)row * DH + col4);
        KsT[col4 + 0][row] = b2f(k4.x);
        KsT[col4 + 1][row] = b2f(k4.y);
        KsT[col4 + 2][row] = b2f(k4.z);
        KsT[col4 + 3][row] = b2f(k4.w);
        const ushort4 v4 = ((const ushort4*)(v_ws + cbase))[f];
        float* vp = &Vs[0][0] + f * 4;
        vp[0] = b2f(v4.x); vp[1] = b2f(v4.y); vp[2] = b2f(v4.z); vp[3] = b2f(v4.w);
    }
    __syncthreads();

    float a[4][4];
#pragma unroll
    for (int i = 0; i < 4; ++i)
#pragma unroll
        for (int j = 0; j < 4; ++j) a[i][j] = 0.0f;
    for (int d = 0; d < 64; ++d) {
        const float4 qd = *(const float4*)&QsT[d][ty * 4];
        const float4 kd = *(const float4*)&KsT[d][tx * 4];
        const float qv[4] = {qd.x, qd.y, qd.z, qd.w};
        const float kv[4] = {kd.x, kd.y, kd.z, kd.w};
#pragma unroll
        for (int i = 0; i < 4; ++i)
#pragma unroll
            for (int j = 0; j < 4; ++j) a[i][j] += qv[i] * kv[j];
    }
#pragma unroll
    for (int i = 0; i < 4; ++i)
#pragma unroll
        for (int j = 0; j < 4; ++j) {
            const int gi = ty * 4 + i, gj = tx * 4 + j;
            As[gi][gj] = (gj <= gi) ? a[i][j] : 0.0f;
        }

    float num[4][4];
#pragma unroll
    for (int i = 0; i < 4; ++i)
#pragma unroll
        for (int j = 0; j < 4; ++j) num[i][j] = 0.0f;
    float den[4] = {0.0f, 0.0f, 0.0f, 0.0f};
#pragma unroll 4
    for (int d = 0; d < 64; ++d) {
        const float4 qd = *(const float4*)&QsT[d][ty * 4];
        const float4 pe = *(const float4*)(pb + d * 64 + tx * 4);
        const float kp = pb[DH * DH + d];
        const float qv[4] = {qd.x, qd.y, qd.z, qd.w};
        const float pv[4] = {pe.x, pe.y, pe.z, pe.w};
#pragma unroll
        for (int i = 0; i < 4; ++i) {
#pragma unroll
            for (int j = 0; j < 4; ++j) num[i][j] += qv[i] * pv[j];
            den[i] += qv[i] * kp;
        }
    }
    __syncthreads();

    float rs[4] = {0.0f, 0.0f, 0.0f, 0.0f};
    for (int j = 0; j < 64; ++j) {
        const float4 ve = *(const float4*)&Vs[j][tx * 4];
        const float vv[4] = {ve.x, ve.y, ve.z, ve.w};
#pragma unroll
        for (int i = 0; i < 4; ++i) {
            const float aij = As[ty * 4 + i][j];
            rs[i] += aij;
            num[i][0] += aij * vv[0];
            num[i][1] += aij * vv[1];
            num[i][2] += aij * vv[2];
            num[i][3] += aij * vv[3];
        }
    }

#pragma unroll
    for (int i = 0; i < 4; ++i) {
        const float dn = den[i] + rs[i];
        const float r  = 1.0f / dn;
        const int srow = c * CHUNK + ty * 4 + i;
        ushort4 o;
        o.x = bf16r(num[i][0] * r); o.y = bf16r(num[i][1] * r);
        o.z = bf16r(num[i][2] * r); o.w = bf16r(num[i][3] * r);
        *(ushort4*)(out_pre + (size_t)srow * DM + h * DH + tx * 4) = o;
    }
}

extern "C" void kernel_launch(void* const* d_in, const int* in_sizes, int n_in,
                              void* d_out, int out_size, void* d_ws, size_t ws_size,
                              hipStream_t stream)
{
    const float* x    = (const float*)d_in[0];
    const float* Wq   = (const float*)d_in[1];
    const float* bq   = (const float*)d_in[2];
    const float* Wk   = (const float*)d_in[3];
    const float* bk   = (const float*)d_in[4];
    const float* Wv   = (const float*)d_in[5];
    const float* bv   = (const float*)d_in[6];
    const float* Wo   = (const float*)d_in[7];
    const float* bo   = (const float*)d_in[8];
    const float* beta = (const float*)d_in[9];
    float* out = (float*)d_out;

    // workspace layout (bf16 q/k/v)
    ushort* q_ws  = (ushort*)d_ws;                           // 3 x 2M bf16 (q|k|v)
    ushort* k_ws  = q_ws + (size_t)NH * S_LEN * DH;
    ushort* v_ws  = k_ws + (size_t)NH * S_LEN * DH;
    float*  st    = (float*)(v_ws + (size_t)NH * S_LEN * DH);      // 16*32*4160 floats
    ushort* x_bf  = (ushort*)(st + (size_t)NH * NCH * ST_STRIDE);  // 2M bf16
    ushort* w_bf  = x_bf + (size_t)S_LEN * DM;                     // 4 x 1M bf16 (Wq|Wk|Wv|Wo)
    ushort* op_bf = w_bf + (size_t)4 * DM * DM;                    // 2M bf16

    const ushort* wo_bf = w_bf + (size_t)3 * DM * DM;

    cast_all_kernel<<<dim3((DM * DM) / 1024, 6), 256, 0, stream>>>(x, Wq, Wk, Wv, Wo, x_bf, w_bf);

    qkv_gemm_kernel<<<768, 256, 0, stream>>>(x_bf, w_bf, bq, bk, bv, beta, q_ws);

    chunk_state_kernel<<<dim3(NCH, NH), 256, 0, stream>>>(k_ws, v_ws, st);
    scan_kernel<<<dim3(ST_STRIDE / 64, NH), 64, 0, stream>>>(st);
    attn_out_kernel<<<dim3(NCH, NH), 256, 0, stream>>>(q_ws, k_ws, v_ws, st, op_bf);

    o_gemm_kernel<<<512, 256, 0, stream>>>(op_bf, wo_bf, bo, out);
}